// Round 8
// baseline (177.544 us; speedup 1.0000x reference)
//
#include <hip/hip_runtime.h>
#include <cstdint>
#include <cstddef>

typedef _Float16 f16;
typedef f16 f16x2 __attribute__((ext_vector_type(2)));
typedef f16 f16x4 __attribute__((ext_vector_type(4)));
typedef f16 f16x8 __attribute__((ext_vector_type(8)));
typedef float f32x4 __attribute__((ext_vector_type(4)));

// ---- fused prep: x f32->f16 cvt (blocks 0..4095), Wqkv transpose
// (blocks 4096..4863), Wproj transpose (4864..5119). ----
__global__ __launch_bounds__(256) void k_prep(const float* __restrict__ x,
                                              const float* __restrict__ Wqkv,
                                              const float* __restrict__ Wproj,
                                              f16* __restrict__ Xh,
                                              f16* __restrict__ WqkvT,
                                              f16* __restrict__ WprojT) {
  const int bid = blockIdx.x, t = threadIdx.x;
  if (bid < 4096) {
    int idx = bid * 256 + t;
    float4 v = ((const float4*)x)[idx];
    f16x4 o;
    o.x = (f16)v.x; o.y = (f16)v.y; o.z = (f16)v.z; o.w = (f16)v.w;
    ((f16x4*)Xh)[idx] = o;
    return;
  }
  const float* in;
  f16* out;
  int N, bx, by;
  if (bid < 4096 + 768) {
    int tb = bid - 4096;
    bx = tb % 48; by = tb / 48; in = Wqkv; out = WqkvT; N = 3072;
  } else {
    int tb = bid - 4096 - 768;
    bx = tb % 16; by = tb / 16; in = Wproj; out = WprojT; N = 1024;
  }
  const int K = 1024;
  __shared__ float tile[64][65];
  const int xx = t & 63, y0 = t >> 6;
#pragma unroll
  for (int r = 0; r < 16; ++r) {
    int y = y0 + r * 4;
    tile[y][xx] = in[(size_t)(by * 64 + y) * N + bx * 64 + xx];
  }
  __syncthreads();
#pragma unroll
  for (int r = 0; r < 16; ++r) {
    int y = y0 + r * 4;
    out[(size_t)(bx * 64 + y) * K + by * 64 + xx] = (f16)tile[xx][y];
  }
}

// ------------- GEMM: C[M][N] = A[M][K] * Bt[N][K]^T  (f16 in, fp32 acc) ----
// Round-3 interleaved staging + XOR swizzle on unpadded 128x64 LDS (proven
// conflict-free, no spills). Best-known GEMM config — unchanged.
template <int F32OUT>
__global__ __launch_bounds__(256) void k_gemm_bt(const f16* __restrict__ A,
                                                 const f16* __restrict__ Bt,
                                                 void* __restrict__ Cout,
                                                 int M, int N, int K) {
  __shared__ __align__(16) f16 As[128 * 64];
  __shared__ __align__(16) f16 Bs[128 * 64];
  const int t = threadIdx.x;
  const int m0 = blockIdx.x * 128, n0 = blockIdx.y * 128;
  const int w = t >> 6, l = t & 63, sl = l & 15, quad = l >> 4;
  const int wm = (w & 1) * 64, wn = (w >> 1) * 64;
  f32x4 acc[4][4] = {};
  const int nk = K >> 6;
  for (int kt = 0; kt < nk; ++kt) {
    __syncthreads();
#pragma unroll
    for (int c = 0; c < 4; ++c) {
      int cid = t + c * 256;
      int row = cid >> 3;
      int ch = cid & 7;
      int ph = ch ^ (row & 7);
      *(uint4*)(As + row * 64 + ph * 8) =
          *(const uint4*)(A + (size_t)(m0 + row) * K + kt * 64 + ch * 8);
      *(uint4*)(Bs + row * 64 + ph * 8) =
          *(const uint4*)(Bt + (size_t)(n0 + row) * K + kt * 64 + ch * 8);
    }
    __syncthreads();
#pragma unroll
    for (int kk = 0; kk < 64; kk += 32) {
      const int cb = kk >> 3;
      f16x8 af[4], bfr[4];
#pragma unroll
      for (int mi = 0; mi < 4; ++mi)
        af[mi] = *(const f16x8*)(As + (wm + mi * 16 + sl) * 64 +
                                 (((cb + quad) ^ (sl & 7)) * 8));
#pragma unroll
      for (int ni = 0; ni < 4; ++ni)
        bfr[ni] = *(const f16x8*)(Bs + (wn + ni * 16 + sl) * 64 +
                                  (((cb + quad) ^ (sl & 7)) * 8));
#pragma unroll
      for (int mi = 0; mi < 4; ++mi)
#pragma unroll
        for (int ni = 0; ni < 4; ++ni)
          acc[mi][ni] = __builtin_amdgcn_mfma_f32_16x16x32_f16(
              af[mi], bfr[ni], acc[mi][ni], 0, 0, 0);
    }
  }
#pragma unroll
  for (int mi = 0; mi < 4; ++mi)
#pragma unroll
    for (int ni = 0; ni < 4; ++ni) {
      int row = m0 + wm + mi * 16 + quad * 4;
      int col = n0 + wn + ni * 16 + sl;
#pragma unroll
      for (int r = 0; r < 4; ++r) {
        if (F32OUT)
          ((float*)Cout)[(size_t)(row + r) * N + col] = acc[mi][ni][r];
        else
          ((f16*)Cout)[(size_t)(row + r) * N + col] = (f16)acc[mi][ni][r];
      }
    }
}

// ---------------- MFMA sparse flash attention ----------------
// K rows now staged ONCE per block into LDS (coalesced); QK^T scores held in
// registers (s[14]) through phase 2a; after a barrier the exp'd P matrix
// aliases the dead Ks region. LDS: Vt 28.9K + max(Ks 32.3K, P 29.7K) + lsum.
__global__ __launch_bounds__(256) void k_attn(const f16* __restrict__ qkv,
                                              f16* __restrict__ y) {
  constexpr int VT = 226;   // Vt pitch (f16): conflict-free scatter writes
  constexpr int KT = 72;    // Ks pitch (f16): 8B-aligned rows, 2-way free
  constexpr int PT = 232;   // P pitch (f16): 16B-aligned rows
  __shared__ __align__(16) char smem[64 * VT * 2 + 224 * KT * 2 + 256];
  f16* Vt = (f16*)smem;                          // 28928 B
  f16* Ks = (f16*)(smem + 64 * VT * 2);          // 32256 B (aliased by P)
  f16* Pb = Ks;                                  // P[4][16*PT] = 29696 B
  float* lsum = (float*)(smem + 64 * VT * 2 + 224 * KT * 2);  // 256 B

  const int t = threadIdx.x, wv = t >> 6, l = t & 63;
  const int sl = l & 15, quad = l >> 4;
  const int blk = blockIdx.x;
  const int qb = blk & 31;
  const int bh = blk >> 5;
  const int b = bh >> 4, h = bh & 15;
  const f16* base = qkv + (size_t)b * 2048 * 3072;
  const int qc = h * 64, kc = 1024 + h * 64, vc = 2048 + h * 64;

  const int row0 = qb * 64;
  const int hi = row0 + 63;
  int lo = row0 - 127; if (lo < 0) lo = 0;
  const int ng = (lo + 63) >> 6;          // globals strictly below window
  const int T = ng + (hi - lo + 1);       // true col count (<=221)
  int NT = (T + 15) >> 4;
  NT = (NT + 1) & ~1;                     // even # of 16-col tiles (<=14)
  const int NC = NT * 16;

  // ---- stage gathered K rows (row-major, coalesced) ----
  for (int cid = t; cid < NC * 8; cid += 256) {
    int idx = cid >> 3, ch = cid & 7;
    int j = idx < ng ? idx * 64 : lo + idx - ng;
    if (idx >= T) j = lo;
    uint4 v = *(const uint4*)(base + (size_t)j * 3072 + kc + ch * 8);
    uint2* dst = (uint2*)(Ks + idx * KT + ch * 8);
    dst[0] = make_uint2(v.x, v.y);
    dst[1] = make_uint2(v.z, v.w);
  }
  // ---- stage gathered V rows transposed: Vt[d][t] ----
  for (int it = 0; it < NC / 8; ++it) {
    int idx = it * 8 + wv * 2 + (l >> 5);
    int j = idx < ng ? idx * 64 : lo + idx - ng;
    if (idx >= T) j = lo;
    int d0 = (l & 31) * 2;
    f16x2 v2 = *(const f16x2*)(base + (size_t)j * 3072 + vc + d0);
    Vt[(d0 + 0) * VT + idx] = v2.x;
    Vt[(d0 + 1) * VT + idx] = v2.y;
  }
  // ---- Q fragments (global, overlaps staging) ----
  const int i0 = row0 + wv * 16;
  f16x8 aq[2];
#pragma unroll
  for (int c = 0; c < 2; ++c) {
    f16x8 qv = *(const f16x8*)(base + (size_t)(i0 + sl) * 3072 + qc + c * 32 +
                               quad * 8);
#pragma unroll
    for (int jj = 0; jj < 8; ++jj) qv[jj] = qv[jj] * (f16)0.125f;
    aq[c] = qv;
  }
  __syncthreads();  // Ks + Vt visible

  // ---- phase 2a: QK^T from LDS Ks, scores in registers, mask, row max ----
  f32x4 s[14];
  float mloc[4] = {-INFINITY, -INFINITY, -INFINITY, -INFINITY};
#pragma unroll
  for (int kt = 0; kt < 14; ++kt) {
    if (kt >= NT) break;
    const int idx = kt * 16 + sl;
    const bool pad = idx >= T;
    int j = idx < ng ? idx * 64 : lo + idx - ng;
    if (pad) j = lo;
    const f16* krow = Ks + idx * KT;
    f16x4 b0a = *(const f16x4*)(krow + quad * 8);
    f16x4 b0b = *(const f16x4*)(krow + quad * 8 + 4);
    f16x4 b1a = *(const f16x4*)(krow + 32 + quad * 8);
    f16x4 b1b = *(const f16x4*)(krow + 32 + quad * 8 + 4);
    f16x8 bk0, bk1;
#pragma unroll
    for (int jj = 0; jj < 4; ++jj) {
      bk0[jj] = b0a[jj]; bk0[4 + jj] = b0b[jj];
      bk1[jj] = b1a[jj]; bk1[4 + jj] = b1b[jj];
    }
    f32x4 z = {0.f, 0.f, 0.f, 0.f};
    z = __builtin_amdgcn_mfma_f32_16x16x32_f16(aq[0], bk0, z, 0, 0, 0);
    z = __builtin_amdgcn_mfma_f32_16x16x32_f16(aq[1], bk1, z, 0, 0, 0);
#pragma unroll
    for (int r = 0; r < 4; ++r) {
      const int i = i0 + quad * 4 + r;
      const bool ok = !pad && (j <= i) && ((i - j) < 128 || (j & 63) == 0);
      z[r] = ok ? z[r] : -INFINITY;
      mloc[r] = fmaxf(mloc[r], z[r]);
    }
    s[kt] = z;
  }
#pragma unroll
  for (int off = 1; off < 16; off <<= 1)
#pragma unroll
    for (int r = 0; r < 4; ++r)
      mloc[r] = fmaxf(mloc[r], __shfl_xor(mloc[r], off, 64));
  __syncthreads();  // all waves done reading Ks; P may now alias it

  // ---- exp in C-layout -> P (f16), row sums in-register ----
  f16* Pw = Pb + wv * 16 * PT;
  float lsr[4] = {0.f, 0.f, 0.f, 0.f};
#pragma unroll
  for (int kt = 0; kt < 14; ++kt) {
    if (kt >= NT) break;
    const int idx = kt * 16 + sl;
#pragma unroll
    for (int r = 0; r < 4; ++r) {
      float p = __expf(s[kt][r] - mloc[r]);
      lsr[r] += p;
      Pw[(quad * 4 + r) * PT + idx] = (f16)p;
    }
  }
#pragma unroll
  for (int off = 1; off < 16; off <<= 1)
#pragma unroll
    for (int r = 0; r < 4; ++r) lsr[r] += __shfl_xor(lsr[r], off, 64);
  if (sl == 0)
#pragma unroll
    for (int r = 0; r < 4; ++r) lsum[wv * 16 + quad * 4 + r] = lsr[r];

  // ---- phase 2b: PV; A-frag = aligned ds_read_b128 of P, B = Vt ----
  const int NKC = NC / 32;
  f32x4 o[4] = {};
  for (int kcc = 0; kcc < NKC; ++kcc) {
    f16x8 ap = *(const f16x8*)(Pw + sl * PT + kcc * 32 + quad * 8);
#pragma unroll
    for (int dt = 0; dt < 4; ++dt) {
      const uint32_t* vb =
          (const uint32_t*)(Vt + (dt * 16 + sl) * VT + kcc * 32 + quad * 8);
      union { uint32_t u[4]; f16x8 v; } cv;
      cv.u[0] = vb[0]; cv.u[1] = vb[1]; cv.u[2] = vb[2]; cv.u[3] = vb[3];
      o[dt] = __builtin_amdgcn_mfma_f32_16x16x32_f16(ap, cv.v, o[dt], 0, 0, 0);
    }
  }
#pragma unroll
  for (int r = 0; r < 4; ++r) {
    const int q = quad * 4 + r;
    const float inv = 1.0f / lsum[wv * 16 + q];
    f16* yr = y + ((size_t)b * 2048 + i0 + q) * 1024 + h * 64;
#pragma unroll
    for (int dt = 0; dt < 4; ++dt) yr[dt * 16 + sl] = (f16)(o[dt][r] * inv);
  }
}

extern "C" void kernel_launch(void* const* d_in, const int* in_sizes, int n_in,
                              void* d_out, int out_size, void* d_ws,
                              size_t ws_size, hipStream_t stream) {
  (void)in_sizes; (void)n_in; (void)out_size; (void)ws_size;
  const float* x = (const float*)d_in[0];
  const float* Wqkv = (const float*)d_in[1];
  const float* Wproj = (const float*)d_in[2];
  float* out = (float*)d_out;
  char* ws = (char*)d_ws;
  f16* Xh     = (f16*)(ws);                         // 4096x1024
  f16* WqkvT  = (f16*)(ws + (size_t)8  * 1048576);  // 3072x1024
  f16* WprojT = (f16*)(ws + (size_t)14 * 1048576);  // 1024x1024
  f16* QKV    = (f16*)(ws + (size_t)16 * 1048576);  // 4096x3072
  f16* Yh     = (f16*)(ws + (size_t)40 * 1048576);  // 4096x1024

  k_prep<<<5120, 256, 0, stream>>>(x, Wqkv, Wproj, Xh, WqkvT, WprojT);
  k_gemm_bt<0><<<dim3(32, 24), 256, 0, stream>>>(Xh, WqkvT, (void*)QKV, 4096,
                                                 3072, 1024);
  k_attn<<<1024, 256, 0, stream>>>(QKV, Yh);
  k_gemm_bt<1><<<dim3(32, 8), 256, 0, stream>>>(Yh, WprojT, (void*)out, 4096,
                                                1024, 1024);
}

// Round 9
// 163.469 us; speedup vs baseline: 1.0861x; 1.0861x over previous
//
#include <hip/hip_runtime.h>
#include <cstdint>
#include <cstddef>

typedef _Float16 f16;
typedef f16 f16x2 __attribute__((ext_vector_type(2)));
typedef f16 f16x4 __attribute__((ext_vector_type(4)));
typedef f16 f16x8 __attribute__((ext_vector_type(8)));
typedef float f32x4 __attribute__((ext_vector_type(4)));

// ---- fused prep: x f32->f16 cvt (blocks 0..4095), Wqkv transpose
// (blocks 4096..4863), Wproj transpose (4864..5119). ----
__global__ __launch_bounds__(256) void k_prep(const float* __restrict__ x,
                                              const float* __restrict__ Wqkv,
                                              const float* __restrict__ Wproj,
                                              f16* __restrict__ Xh,
                                              f16* __restrict__ WqkvT,
                                              f16* __restrict__ WprojT) {
  const int bid = blockIdx.x, t = threadIdx.x;
  if (bid < 4096) {
    int idx = bid * 256 + t;
    float4 v = ((const float4*)x)[idx];
    f16x4 o;
    o.x = (f16)v.x; o.y = (f16)v.y; o.z = (f16)v.z; o.w = (f16)v.w;
    ((f16x4*)Xh)[idx] = o;
    return;
  }
  const float* in;
  f16* out;
  int N, bx, by;
  if (bid < 4096 + 768) {
    int tb = bid - 4096;
    bx = tb % 48; by = tb / 48; in = Wqkv; out = WqkvT; N = 3072;
  } else {
    int tb = bid - 4096 - 768;
    bx = tb % 16; by = tb / 16; in = Wproj; out = WprojT; N = 1024;
  }
  const int K = 1024;
  __shared__ float tile[64][65];
  const int xx = t & 63, y0 = t >> 6;
#pragma unroll
  for (int r = 0; r < 16; ++r) {
    int y = y0 + r * 4;
    tile[y][xx] = in[(size_t)(by * 64 + y) * N + bx * 64 + xx];
  }
  __syncthreads();
#pragma unroll
  for (int r = 0; r < 16; ++r) {
    int y = y0 + r * 4;
    out[(size_t)(bx * 64 + y) * K + by * 64 + xx] = (f16)tile[xx][y];
  }
}

// ------------- GEMM: C[M][N] = A[M][K] * Bt[N][K]^T  (f16 in, fp32 acc) ----
// Round-3 interleaved staging + XOR swizzle on unpadded 128x64 LDS (proven
// conflict-free, no spills). Best-known GEMM config — unchanged.
template <int F32OUT>
__global__ __launch_bounds__(256) void k_gemm_bt(const f16* __restrict__ A,
                                                 const f16* __restrict__ Bt,
                                                 void* __restrict__ Cout,
                                                 int M, int N, int K) {
  __shared__ __align__(16) f16 As[128 * 64];
  __shared__ __align__(16) f16 Bs[128 * 64];
  const int t = threadIdx.x;
  const int m0 = blockIdx.x * 128, n0 = blockIdx.y * 128;
  const int w = t >> 6, l = t & 63, sl = l & 15, quad = l >> 4;
  const int wm = (w & 1) * 64, wn = (w >> 1) * 64;
  f32x4 acc[4][4] = {};
  const int nk = K >> 6;
  for (int kt = 0; kt < nk; ++kt) {
    __syncthreads();
#pragma unroll
    for (int c = 0; c < 4; ++c) {
      int cid = t + c * 256;
      int row = cid >> 3;
      int ch = cid & 7;
      int ph = ch ^ (row & 7);
      *(uint4*)(As + row * 64 + ph * 8) =
          *(const uint4*)(A + (size_t)(m0 + row) * K + kt * 64 + ch * 8);
      *(uint4*)(Bs + row * 64 + ph * 8) =
          *(const uint4*)(Bt + (size_t)(n0 + row) * K + kt * 64 + ch * 8);
    }
    __syncthreads();
#pragma unroll
    for (int kk = 0; kk < 64; kk += 32) {
      const int cb = kk >> 3;
      f16x8 af[4], bfr[4];
#pragma unroll
      for (int mi = 0; mi < 4; ++mi)
        af[mi] = *(const f16x8*)(As + (wm + mi * 16 + sl) * 64 +
                                 (((cb + quad) ^ (sl & 7)) * 8));
#pragma unroll
      for (int ni = 0; ni < 4; ++ni)
        bfr[ni] = *(const f16x8*)(Bs + (wn + ni * 16 + sl) * 64 +
                                  (((cb + quad) ^ (sl & 7)) * 8));
#pragma unroll
      for (int mi = 0; mi < 4; ++mi)
#pragma unroll
        for (int ni = 0; ni < 4; ++ni)
          acc[mi][ni] = __builtin_amdgcn_mfma_f32_16x16x32_f16(
              af[mi], bfr[ni], acc[mi][ni], 0, 0, 0);
    }
  }
#pragma unroll
  for (int mi = 0; mi < 4; ++mi)
#pragma unroll
    for (int ni = 0; ni < 4; ++ni) {
      int row = m0 + wm + mi * 16 + quad * 4;
      int col = n0 + wn + ni * 16 + sl;
#pragma unroll
      for (int r = 0; r < 4; ++r) {
        if (F32OUT)
          ((float*)Cout)[(size_t)(row + r) * N + col] = acc[mi][ni][r];
        else
          ((f16*)Cout)[(size_t)(row + r) * N + col] = (f16)acc[mi][ni][r];
      }
    }
}

// ---------------- MFMA sparse flash attention (phased LDS) ----------------
// Phase 1: stage gathered K rows coalesced into Ks (144 B rows, 16B-aligned).
// Phase 2: QK^T with B-frags from Ks via ds_read_b128; raw f16 scores -> P
//          (separate LDS region, NO register score array -> no spills).
// Phase 3: after barrier (Ks dead) stage V transposed into the SAME region.
// Phase 4: PV with exp(P - rmax) A-frags (round-7 proven code).
__global__ __launch_bounds__(256) void k_attn(const f16* __restrict__ qkv,
                                              f16* __restrict__ y) {
  constexpr int VT = 226;  // Vt pitch: odd dword rows -> cf scatter writes
  constexpr int KT = 72;   // Ks pitch: 144 B rows (16B-aligned), 2-way banks
  constexpr int PT = 232;  // P pitch: 464 B rows, 2-way banks
  __shared__ __align__(16) char smem[224 * KT * 2 + 4 * 16 * PT * 2 + 512];
  f16* Ks = (f16*)smem;                  // 32256 B
  f16* Vt = (f16*)smem;                  // 28928 B, aliases Ks (phase 3+)
  f16* Pb = (f16*)(smem + 224 * KT * 2); // 29696 B
  float* rmax = (float*)(smem + 224 * KT * 2 + 4 * 16 * PT * 2);  // 64 f
  float* lsum = rmax + 64;                                        // 64 f

  const int t = threadIdx.x, wv = t >> 6, l = t & 63;
  const int sl = l & 15, quad = l >> 4;
  const int blk = blockIdx.x;
  const int qb = blk & 31;
  const int bh = blk >> 5;
  const int b = bh >> 4, h = bh & 15;
  const f16* base = qkv + (size_t)b * 2048 * 3072;
  const int qc = h * 64, kc = 1024 + h * 64, vc = 2048 + h * 64;

  const int row0 = qb * 64;
  const int hi = row0 + 63;
  int lo = row0 - 127; if (lo < 0) lo = 0;
  const int ng = (lo + 63) >> 6;          // globals strictly below window
  const int T = ng + (hi - lo + 1);       // true col count (<=221)
  int NT = (T + 15) >> 4;
  NT = (NT + 1) & ~1;                     // even # of 16-col tiles (<=14)
  const int NC = NT * 16;

  // ---- phase 1: stage gathered K rows (row-major, coalesced uint4) ----
  for (int cid = t; cid < NC * 8; cid += 256) {
    int idx = cid >> 3, ch = cid & 7;
    int j = idx < ng ? idx * 64 : lo + idx - ng;
    if (idx >= T) j = lo;
    *(uint4*)(Ks + idx * KT + ch * 8) =
        *(const uint4*)(base + (size_t)j * 3072 + kc + ch * 8);
  }
  // ---- Q fragments (global; overlaps staging) ----
  const int i0 = row0 + wv * 16;
  f16x8 aq[2];
#pragma unroll
  for (int c = 0; c < 2; ++c) {
    f16x8 qv = *(const f16x8*)(base + (size_t)(i0 + sl) * 3072 + qc + c * 32 +
                               quad * 8);
#pragma unroll
    for (int jj = 0; jj < 8; ++jj) qv[jj] = qv[jj] * (f16)0.125f;
    aq[c] = qv;
  }
  __syncthreads();  // Ks visible

  // ---- phase 2: QK^T from Ks, mask, raw f16 scores -> P, row max ----
  f16* Pw = Pb + wv * 16 * PT;
  float mloc[4] = {-INFINITY, -INFINITY, -INFINITY, -INFINITY};
  for (int kt = 0; kt < NT; ++kt) {
    const int idx = kt * 16 + sl;
    const bool pad = idx >= T;
    int j = idx < ng ? idx * 64 : lo + idx - ng;
    if (pad) j = lo;
    const f16* krow = Ks + idx * KT;
    f16x8 bk0 = *(const f16x8*)(krow + quad * 8);
    f16x8 bk1 = *(const f16x8*)(krow + 32 + quad * 8);
    f32x4 s = {0.f, 0.f, 0.f, 0.f};
    s = __builtin_amdgcn_mfma_f32_16x16x32_f16(aq[0], bk0, s, 0, 0, 0);
    s = __builtin_amdgcn_mfma_f32_16x16x32_f16(aq[1], bk1, s, 0, 0, 0);
#pragma unroll
    for (int r = 0; r < 4; ++r) {
      const int i = i0 + quad * 4 + r;
      const bool ok = !pad && (j <= i) && ((i - j) < 128 || (j & 63) == 0);
      const float sv = ok ? s[r] : -INFINITY;
      mloc[r] = fmaxf(mloc[r], sv);
      Pw[(quad * 4 + r) * PT + idx] = (f16)sv;
    }
  }
#pragma unroll
  for (int off = 1; off < 16; off <<= 1)
#pragma unroll
    for (int r = 0; r < 4; ++r)
      mloc[r] = fmaxf(mloc[r], __shfl_xor(mloc[r], off, 64));
  if (sl == 0)
#pragma unroll
    for (int r = 0; r < 4; ++r) rmax[wv * 16 + quad * 4 + r] = mloc[r];
  __syncthreads();  // all Ks reads done; P + rmax visible

  // ---- phase 3: stage gathered V rows transposed over dead Ks ----
  for (int it = 0; it < NC / 8; ++it) {
    int idx = it * 8 + wv * 2 + (l >> 5);
    int j = idx < ng ? idx * 64 : lo + idx - ng;
    if (idx >= T) j = lo;
    int d0 = (l & 31) * 2;
    f16x2 v2 = *(const f16x2*)(base + (size_t)j * 3072 + vc + d0);
    Vt[(d0 + 0) * VT + idx] = v2.x;
    Vt[(d0 + 1) * VT + idx] = v2.y;
  }
  __syncthreads();  // Vt visible

  // ---- phase 4: PV with exp(P - m) as A-frags, Vt as B-frags ----
  const int NKC = NC / 32;
  f32x4 o[4] = {};
  float ls = 0.f;
  const float mrow = rmax[wv * 16 + sl];
  for (int kcc = 0; kcc < NKC; ++kcc) {
    f16x8 raw = *(const f16x8*)(Pw + sl * PT + kcc * 32 + quad * 8);
    f16x8 ap;
#pragma unroll
    for (int jj = 0; jj < 8; ++jj) {
      float p = __expf((float)raw[jj] - mrow);
      ls += p;
      ap[jj] = (f16)p;
    }
#pragma unroll
    for (int dt = 0; dt < 4; ++dt) {
      const uint32_t* vb =
          (const uint32_t*)(Vt + (dt * 16 + sl) * VT + kcc * 32 + quad * 8);
      union { uint32_t u[4]; f16x8 v; } cv;
      cv.u[0] = vb[0]; cv.u[1] = vb[1]; cv.u[2] = vb[2]; cv.u[3] = vb[3];
      o[dt] = __builtin_amdgcn_mfma_f32_16x16x32_f16(ap, cv.v, o[dt], 0, 0, 0);
    }
  }
  ls += __shfl_xor(ls, 16, 64);
  ls += __shfl_xor(ls, 32, 64);
  if (quad == 0) lsum[wv * 16 + sl] = ls;
  __syncthreads();
#pragma unroll
  for (int r = 0; r < 4; ++r) {
    const int q = quad * 4 + r;
    const float inv = 1.0f / lsum[wv * 16 + q];
    f16* yr = y + ((size_t)b * 2048 + i0 + q) * 1024 + h * 64;
#pragma unroll
    for (int dt = 0; dt < 4; ++dt) yr[dt * 16 + sl] = (f16)(o[dt][r] * inv);
  }
}

extern "C" void kernel_launch(void* const* d_in, const int* in_sizes, int n_in,
                              void* d_out, int out_size, void* d_ws,
                              size_t ws_size, hipStream_t stream) {
  (void)in_sizes; (void)n_in; (void)out_size; (void)ws_size;
  const float* x = (const float*)d_in[0];
  const float* Wqkv = (const float*)d_in[1];
  const float* Wproj = (const float*)d_in[2];
  float* out = (float*)d_out;
  char* ws = (char*)d_ws;
  f16* Xh     = (f16*)(ws);                         // 4096x1024
  f16* WqkvT  = (f16*)(ws + (size_t)8  * 1048576);  // 3072x1024
  f16* WprojT = (f16*)(ws + (size_t)14 * 1048576);  // 1024x1024
  f16* QKV    = (f16*)(ws + (size_t)16 * 1048576);  // 4096x3072
  f16* Yh     = (f16*)(ws + (size_t)40 * 1048576);  // 4096x1024

  k_prep<<<5120, 256, 0, stream>>>(x, Wqkv, Wproj, Xh, WqkvT, WprojT);
  k_gemm_bt<0><<<dim3(32, 24), 256, 0, stream>>>(Xh, WqkvT, (void*)QKV, 4096,
                                                 3072, 1024);
  k_attn<<<1024, 256, 0, stream>>>(QKV, Yh);
  k_gemm_bt<1><<<dim3(32, 8), 256, 0, stream>>>(Yh, WprojT, (void*)out, 4096,
                                                1024, 1024);
}

// Round 10
// 161.763 us; speedup vs baseline: 1.0976x; 1.0105x over previous
//
#include <hip/hip_runtime.h>
#include <cstdint>
#include <cstddef>

typedef _Float16 f16;
typedef f16 f16x2 __attribute__((ext_vector_type(2)));
typedef f16 f16x4 __attribute__((ext_vector_type(4)));
typedef f16 f16x8 __attribute__((ext_vector_type(8)));
typedef float f32x4 __attribute__((ext_vector_type(4)));

// ---- fused prep. Heavy transpose blocks FIRST (0..767 Wqkv, 768..1023
// Wproj), then x f32->f16 cvt (1024..5119) — better tail balance. ----
__global__ __launch_bounds__(256) void k_prep(const float* __restrict__ x,
                                              const float* __restrict__ Wqkv,
                                              const float* __restrict__ Wproj,
                                              f16* __restrict__ Xh,
                                              f16* __restrict__ WqkvT,
                                              f16* __restrict__ WprojT) {
  const int bid = blockIdx.x, t = threadIdx.x;
  if (bid >= 1024) {
    int idx = (bid - 1024) * 256 + t;
    float4 v = ((const float4*)x)[idx];
    f16x4 o;
    o.x = (f16)v.x; o.y = (f16)v.y; o.z = (f16)v.z; o.w = (f16)v.w;
    ((f16x4*)Xh)[idx] = o;
    return;
  }
  const float* in;
  f16* out;
  int N, bx, by;
  if (bid < 768) {
    bx = bid % 48; by = bid / 48; in = Wqkv; out = WqkvT; N = 3072;
  } else {
    int tb = bid - 768;
    bx = tb % 16; by = tb / 16; in = Wproj; out = WprojT; N = 1024;
  }
  const int K = 1024;
  __shared__ float tile[64][65];
  const int xx = t & 63, y0 = t >> 6;
#pragma unroll
  for (int r = 0; r < 16; ++r) {
    int y = y0 + r * 4;
    tile[y][xx] = in[(size_t)(by * 64 + y) * N + bx * 64 + xx];
  }
  __syncthreads();
#pragma unroll
  for (int r = 0; r < 16; ++r) {
    int y = y0 + r * 4;
    out[(size_t)(bx * 64 + y) * K + by * 64 + xx] = (f16)tile[xx][y];
  }
}

// ------------- GEMM: C[M][N] = A[M][K] * Bt[N][K]^T  (f16 in, fp32 acc) ----
// Round-3 interleaved staging + XOR swizzle on unpadded 128x64 LDS (proven
// conflict-free, no spills). Best-known GEMM config — unchanged.
template <int F32OUT>
__global__ __launch_bounds__(256) void k_gemm_bt(const f16* __restrict__ A,
                                                 const f16* __restrict__ Bt,
                                                 void* __restrict__ Cout,
                                                 int M, int N, int K) {
  __shared__ __align__(16) f16 As[128 * 64];
  __shared__ __align__(16) f16 Bs[128 * 64];
  const int t = threadIdx.x;
  const int m0 = blockIdx.x * 128, n0 = blockIdx.y * 128;
  const int w = t >> 6, l = t & 63, sl = l & 15, quad = l >> 4;
  const int wm = (w & 1) * 64, wn = (w >> 1) * 64;
  f32x4 acc[4][4] = {};
  const int nk = K >> 6;
  for (int kt = 0; kt < nk; ++kt) {
    __syncthreads();
#pragma unroll
    for (int c = 0; c < 4; ++c) {
      int cid = t + c * 256;
      int row = cid >> 3;
      int ch = cid & 7;
      int ph = ch ^ (row & 7);
      *(uint4*)(As + row * 64 + ph * 8) =
          *(const uint4*)(A + (size_t)(m0 + row) * K + kt * 64 + ch * 8);
      *(uint4*)(Bs + row * 64 + ph * 8) =
          *(const uint4*)(Bt + (size_t)(n0 + row) * K + kt * 64 + ch * 8);
    }
    __syncthreads();
#pragma unroll
    for (int kk = 0; kk < 64; kk += 32) {
      const int cb = kk >> 3;
      f16x8 af[4], bfr[4];
#pragma unroll
      for (int mi = 0; mi < 4; ++mi)
        af[mi] = *(const f16x8*)(As + (wm + mi * 16 + sl) * 64 +
                                 (((cb + quad) ^ (sl & 7)) * 8));
#pragma unroll
      for (int ni = 0; ni < 4; ++ni)
        bfr[ni] = *(const f16x8*)(Bs + (wn + ni * 16 + sl) * 64 +
                                  (((cb + quad) ^ (sl & 7)) * 8));
#pragma unroll
      for (int mi = 0; mi < 4; ++mi)
#pragma unroll
        for (int ni = 0; ni < 4; ++ni)
          acc[mi][ni] = __builtin_amdgcn_mfma_f32_16x16x32_f16(
              af[mi], bfr[ni], acc[mi][ni], 0, 0, 0);
    }
  }
#pragma unroll
  for (int mi = 0; mi < 4; ++mi)
#pragma unroll
    for (int ni = 0; ni < 4; ++ni) {
      int row = m0 + wm + mi * 16 + quad * 4;
      int col = n0 + wn + ni * 16 + sl;
#pragma unroll
      for (int r = 0; r < 4; ++r) {
        if (F32OUT)
          ((float*)Cout)[(size_t)(row + r) * N + col] = acc[mi][ni][r];
        else
          ((f16*)Cout)[(size_t)(row + r) * N + col] = (f16)acc[mi][ni][r];
      }
    }
}

// ---------------- MFMA sparse flash attention (phased LDS) ----------------
// Round-9 structure; V staging now COALESCED uint4 row loads (like Ks) with
// in-register transpose scatter to Vt — kills the serial 4B-gather latency.
__global__ __launch_bounds__(256) void k_attn(const f16* __restrict__ qkv,
                                              f16* __restrict__ y) {
  constexpr int VT = 226;  // Vt pitch: 4-way write aliasing, cf b128 reads
  constexpr int KT = 72;   // Ks pitch: 144 B rows (16B-aligned), 2-way banks
  constexpr int PT = 232;  // P pitch: 464 B rows, 2-way banks
  __shared__ __align__(16) char smem[224 * KT * 2 + 4 * 16 * PT * 2 + 512];
  f16* Ks = (f16*)smem;                  // 32256 B
  f16* Vt = (f16*)smem;                  // 28928 B, aliases Ks (phase 3+)
  f16* Pb = (f16*)(smem + 224 * KT * 2); // 29696 B
  float* rmax = (float*)(smem + 224 * KT * 2 + 4 * 16 * PT * 2);  // 64 f
  float* lsum = rmax + 64;                                        // 64 f

  const int t = threadIdx.x, wv = t >> 6, l = t & 63;
  const int sl = l & 15, quad = l >> 4;
  const int blk = blockIdx.x;
  const int qb = blk & 31;
  const int bh = blk >> 5;
  const int b = bh >> 4, h = bh & 15;
  const f16* base = qkv + (size_t)b * 2048 * 3072;
  const int qc = h * 64, kc = 1024 + h * 64, vc = 2048 + h * 64;

  const int row0 = qb * 64;
  const int hi = row0 + 63;
  int lo = row0 - 127; if (lo < 0) lo = 0;
  const int ng = (lo + 63) >> 6;          // globals strictly below window
  const int T = ng + (hi - lo + 1);       // true col count (<=221)
  int NT = (T + 15) >> 4;
  NT = (NT + 1) & ~1;                     // even # of 16-col tiles (<=14)
  const int NC = NT * 16;

  // ---- phase 1: stage gathered K rows (row-major, coalesced uint4) ----
  for (int cid = t; cid < NC * 8; cid += 256) {
    int idx = cid >> 3, ch = cid & 7;
    int j = idx < ng ? idx * 64 : lo + idx - ng;
    if (idx >= T) j = lo;
    *(uint4*)(Ks + idx * KT + ch * 8) =
        *(const uint4*)(base + (size_t)j * 3072 + kc + ch * 8);
  }
  // ---- Q fragments (global; overlaps staging) ----
  const int i0 = row0 + wv * 16;
  f16x8 aq[2];
#pragma unroll
  for (int c = 0; c < 2; ++c) {
    f16x8 qv = *(const f16x8*)(base + (size_t)(i0 + sl) * 3072 + qc + c * 32 +
                               quad * 8);
#pragma unroll
    for (int jj = 0; jj < 8; ++jj) qv[jj] = qv[jj] * (f16)0.125f;
    aq[c] = qv;
  }
  __syncthreads();  // Ks visible

  // ---- phase 2: QK^T from Ks, mask, raw f16 scores -> P, row max ----
  f16* Pw = Pb + wv * 16 * PT;
  float mloc[4] = {-INFINITY, -INFINITY, -INFINITY, -INFINITY};
  for (int kt = 0; kt < NT; ++kt) {
    const int idx = kt * 16 + sl;
    const bool pad = idx >= T;
    int j = idx < ng ? idx * 64 : lo + idx - ng;
    if (pad) j = lo;
    const f16* krow = Ks + idx * KT;
    f16x8 bk0 = *(const f16x8*)(krow + quad * 8);
    f16x8 bk1 = *(const f16x8*)(krow + 32 + quad * 8);
    f32x4 s = {0.f, 0.f, 0.f, 0.f};
    s = __builtin_amdgcn_mfma_f32_16x16x32_f16(aq[0], bk0, s, 0, 0, 0);
    s = __builtin_amdgcn_mfma_f32_16x16x32_f16(aq[1], bk1, s, 0, 0, 0);
#pragma unroll
    for (int r = 0; r < 4; ++r) {
      const int i = i0 + quad * 4 + r;
      const bool ok = !pad && (j <= i) && ((i - j) < 128 || (j & 63) == 0);
      const float sv = ok ? s[r] : -INFINITY;
      mloc[r] = fmaxf(mloc[r], sv);
      Pw[(quad * 4 + r) * PT + idx] = (f16)sv;
    }
  }
#pragma unroll
  for (int off = 1; off < 16; off <<= 1)
#pragma unroll
    for (int r = 0; r < 4; ++r)
      mloc[r] = fmaxf(mloc[r], __shfl_xor(mloc[r], off, 64));
  if (sl == 0)
#pragma unroll
    for (int r = 0; r < 4; ++r) rmax[wv * 16 + quad * 4 + r] = mloc[r];
  __syncthreads();  // all Ks reads done; P + rmax visible

  // ---- phase 3: stage V rows transposed over dead Ks — coalesced uint4
  // loads (8 lanes cover one 128 B row), 8 b16 scatter-writes per thread ----
  for (int cid = t; cid < NC * 8; cid += 256) {
    int idx = cid >> 3, ch = cid & 7;
    int j = idx < ng ? idx * 64 : lo + idx - ng;
    if (idx >= T) j = lo;
    f16x8 v8 = *(const f16x8*)(base + (size_t)j * 3072 + vc + ch * 8);
#pragma unroll
    for (int jj = 0; jj < 8; ++jj) Vt[(ch * 8 + jj) * VT + idx] = v8[jj];
  }
  __syncthreads();  // Vt visible

  // ---- phase 4: PV with exp(P - m) as A-frags, Vt as B-frags ----
  const int NKC = NC / 32;
  f32x4 o[4] = {};
  float ls = 0.f;
  const float mrow = rmax[wv * 16 + sl];
  for (int kcc = 0; kcc < NKC; ++kcc) {
    f16x8 raw = *(const f16x8*)(Pw + sl * PT + kcc * 32 + quad * 8);
    f16x8 ap;
#pragma unroll
    for (int jj = 0; jj < 8; ++jj) {
      float p = __expf((float)raw[jj] - mrow);
      ls += p;
      ap[jj] = (f16)p;
    }
#pragma unroll
    for (int dt = 0; dt < 4; ++dt) {
      const uint32_t* vb =
          (const uint32_t*)(Vt + (dt * 16 + sl) * VT + kcc * 32 + quad * 8);
      union { uint32_t u[4]; f16x8 v; } cv;
      cv.u[0] = vb[0]; cv.u[1] = vb[1]; cv.u[2] = vb[2]; cv.u[3] = vb[3];
      o[dt] = __builtin_amdgcn_mfma_f32_16x16x32_f16(ap, cv.v, o[dt], 0, 0, 0);
    }
  }
  ls += __shfl_xor(ls, 16, 64);
  ls += __shfl_xor(ls, 32, 64);
  if (quad == 0) lsum[wv * 16 + sl] = ls;
  __syncthreads();
#pragma unroll
  for (int r = 0; r < 4; ++r) {
    const int q = quad * 4 + r;
    const float inv = 1.0f / lsum[wv * 16 + q];
    f16* yr = y + ((size_t)b * 2048 + i0 + q) * 1024 + h * 64;
#pragma unroll
    for (int dt = 0; dt < 4; ++dt) yr[dt * 16 + sl] = (f16)(o[dt][r] * inv);
  }
}

extern "C" void kernel_launch(void* const* d_in, const int* in_sizes, int n_in,
                              void* d_out, int out_size, void* d_ws,
                              size_t ws_size, hipStream_t stream) {
  (void)in_sizes; (void)n_in; (void)out_size; (void)ws_size;
  const float* x = (const float*)d_in[0];
  const float* Wqkv = (const float*)d_in[1];
  const float* Wproj = (const float*)d_in[2];
  float* out = (float*)d_out;
  char* ws = (char*)d_ws;
  f16* Xh     = (f16*)(ws);                         // 4096x1024
  f16* WqkvT  = (f16*)(ws + (size_t)8  * 1048576);  // 3072x1024
  f16* WprojT = (f16*)(ws + (size_t)14 * 1048576);  // 1024x1024
  f16* QKV    = (f16*)(ws + (size_t)16 * 1048576);  // 4096x3072
  f16* Yh     = (f16*)(ws + (size_t)40 * 1048576);  // 4096x1024

  k_prep<<<5120, 256, 0, stream>>>(x, Wqkv, Wproj, Xh, WqkvT, WprojT);
  k_gemm_bt<0><<<dim3(32, 24), 256, 0, stream>>>(Xh, WqkvT, (void*)QKV, 4096,
                                                 3072, 1024);
  k_attn<<<1024, 256, 0, stream>>>(QKV, Yh);
  k_gemm_bt<1><<<dim3(32, 8), 256, 0, stream>>>(Yh, WprojT, (void*)out, 4096,
                                                1024, 1024);
}